// Round 9
// baseline (54.420 us; speedup 1.0000x reference)
//
#include <hip/hip_runtime.h>

// STN forward, LDS-tiled, ONE 70.6KB channel buffer, two passes (R8 structure).
// R9: shave VGPR below the 64-reg occupancy cliff (64 -> 4 waves/SIMD, m69;
// R8 measured 38% occupancy at VGPR=64) so 2 blocks/CU co-reside and staging
// hides under the other block's compute. Levers: (1) branchless hot gather
// (fallback lanes produce garbage that is fully overwritten by a cold path
// after the loop), (2) sched_barrier(0) between k iterations to stop the
// scheduler from interleaving all 4 k's live ranges.
// NO waves_per_eu/min-waves attr (R5/R6: catastrophic scratch spills).

constexpr int B = 2, C = 2, D = 128, H = 128, W = 128;
constexpr int HW  = H * W;
constexpr int DHW = D * HW;
constexpr int TD = 16, TH = 16, TW = 16;     // output tile
constexpr int HALO = 4;
constexpr int RD = 25, RH = 25, RWP = 28;    // staged region (w padded: 7 granules)
constexpr int CHF = RD * RH * RWP;           // 17500 floats / channel
constexpr int CHG = CHF / 4;                 // 4375 16B granules / channel
constexpr int NT = 1024;
constexpr int CHG_PAD = 4416;                // 69 waves (wave-multiple)
constexpr int TAIL = CHG_PAD - 4 * NT;       // 320 = 5 full waves

__device__ __forceinline__ void gload_lds16(const float* g, float* l) {
    __builtin_amdgcn_global_load_lds(
        (const __attribute__((address_space(1))) void*)g,
        (__attribute__((address_space(3))) void*)l, 16, 0, 0);
}

__global__ __launch_bounds__(NT) void stn_kernel(
    const float* __restrict__ image,
    const float* __restrict__ ddf,
    float* __restrict__ out)
{
    __shared__ float smem[CHG_PAD * 4];      // 70656 B -> 2 blocks/CU (if VGPR<64)

    const int blk = blockIdx.x;
    const int b   = blk >> 9;
    const int tb  = blk & 511;
    const int t0d = (tb >> 6) * TD, t0h = ((tb >> 3) & 7) * TH, t0w = (tb & 7) * TW;
    const int lo_d = max(t0d - HALO, 0), lo_h = max(t0h - HALO, 0), lo_w = max(t0w - HALO, 0);
    const int hi_d = min(t0d + TD + HALO, D - 1);
    const int hi_h = min(t0h + TH + HALO, H - 1);
    const int hi_w = min(t0w + TW + HALO, W - 1);
    const float* imgb = image + (size_t)b * C * DHW;
    const int tid = threadIdx.x;

    // ---- ddf loads FIRST ----
    const int dl = tid >> 6, hl = (tid >> 2) & 15, wq = tid & 3;
    const int d = t0d + dl, h = t0h + hl, w4 = t0w + wq * 4;
    const int sidx = d * HW + h * W + w4;
    const float* dp = ddf + (size_t)b * 3 * DHW + sidx;
    float4 fdd = *reinterpret_cast<const float4*>(dp);
    float4 fdh = *reinterpret_cast<const float4*>(dp + DHW);
    float4 fdw = *reinterpret_cast<const float4*>(dp + 2 * DHW);
    asm volatile("" ::: "memory");

    // granule g -> global offset (row-clamped at volume edge)
    auto gsrc_off = [&](int g) {
        int row = g / 7;
        int rw  = (g - row * 7) * 4;
        int rd  = row / RH;
        int rh  = row - rd * RH;
        return min(lo_d + rd, D - 1) * HW + min(lo_h + rh, H - 1) * W
             + min(lo_w + rw, W - 4);
    };

    // async stage one channel into smem; tail is 5 whole waves
    auto issue_stage = [&](const float* src) {
#pragma unroll
        for (int i = 0; i < 4; ++i) {
            int g = tid + i * NT;                       // < 4096 < CHG
            gload_lds16(src + gsrc_off(g), &smem[g * 4]);
        }
        if (tid < TAIL) {                               // whole-wave branch
            int g = tid + 4 * NT;                       // 4096..4415
            int gq = min(g, CHG - 1);                   // clamp SOURCE only
            gload_lds16(src + gsrc_off(gq), &smem[g * 4]);
        }
    };

    issue_stage(imgb);                                  // ch0 in flight
    asm volatile("" ::: "memory");

    // clamped coords (persisted across both passes; 12 VGPR)
    float cdk[4], chk[4], cwk[4];
    {
        const float dd[4] = {fdd.x, fdd.y, fdd.z, fdd.w};
        const float dh[4] = {fdh.x, fdh.y, fdh.z, fdh.w};
        const float dw[4] = {fdw.x, fdw.y, fdw.z, fdw.w};
#pragma unroll
        for (int k = 0; k < 4; ++k) {
            cdk[k] = fminf(fmaxf((float)d + dd[k], 0.0f), (float)(D - 1));
            chk[k] = fminf(fmaxf((float)h + dh[k], 0.0f), (float)(H - 1));
            cwk[k] = fminf(fmaxf((float)(w4 + k) + dw[k], 0.0f), (float)(W - 1));
        }
    }

    // branchless LDS gather; returns fallback mask (bit k set -> acc[k]
    // is garbage and must be recomputed from global). sched_barrier(0)
    // between ks keeps the 4 iterations' live ranges from overlapping.
    auto gather = [&](float* acc) -> int {
        int fb = 0;
#pragma unroll
        for (int k = 0; k < 4; ++k) {
            float cd = cdk[k], ch = chk[k], cw = cwk[k];
            float d0f = floorf(cd), h0f = floorf(ch), w0f = floorf(cw);
            float fd = cd - d0f, fh = ch - h0f, fw = cw - w0f;
            int d0 = (int)d0f, h0 = (int)h0f, w0 = (int)w0f;
            bool bad = (d0 < lo_d) | (d0 + 1 > hi_d) | (h0 < lo_h) | (h0 + 1 > hi_h)
                     | (w0 < lo_w) | (w0 + 1 > hi_w)
                     | (d0 >= D - 1) | (h0 >= H - 1) | (w0 >= W - 1);
            // note: d0==D-1 (coord exactly at top border) is sent to the
            // cold path so the hot path needs no min(d0+1,D-1) clamps.
            fb |= (int)bad << k;
            float gd = 1.0f - fd, gh = 1.0f - fh, gw = 1.0f - fw;
            float w00 = gh * gw, w01 = gh * fw, w10 = fh * gw, w11 = fh * fw;
            int ld0 = d0 - lo_d, lh0 = h0 - lo_h, lw0 = w0 - lo_w;
            int i00 = (ld0 * RH + lh0) * RWP + lw0;
            int i01 = i00 + RWP;                 // h0+1
            int i10 = i00 + RH * RWP;            // d0+1
            int i11 = i10 + RWP;
            float p0 = smem[i00] * w00 + smem[i00 + 1] * w01
                     + smem[i01] * w10 + smem[i01 + 1] * w11;
            float p1 = smem[i10] * w00 + smem[i10 + 1] * w01
                     + smem[i11] * w10 + smem[i11 + 1] * w11;
            acc[k] = gd * p0 + fd * p1;          // garbage if bad (overwritten)
            __builtin_amdgcn_sched_barrier(0);
        }
        return fb;
    };

    // rare cold path: exact global recompute for flagged ks
    auto fixup = [&](const float* gimg, float* acc, int fb) {
        if (fb) {
#pragma unroll
            for (int k = 0; k < 4; ++k) {
                if (fb & (1 << k)) {
                    float cd = cdk[k], ch = chk[k], cw = cwk[k];
                    float d0f = floorf(cd), h0f = floorf(ch), w0f = floorf(cw);
                    float fd = cd - d0f, fh = ch - h0f, fw = cw - w0f;
                    int d0 = (int)d0f, h0 = (int)h0f, w0 = (int)w0f;
                    int d1 = min(d0 + 1, D - 1);
                    int h1 = min(h0 + 1, H - 1);
                    int w1 = min(w0 + 1, W - 1);
                    float gd = 1.0f - fd, gh = 1.0f - fh, gw = 1.0f - fw;
                    float w00 = gh * gw, w01 = gh * fw, w10 = fh * gw, w11 = fh * fw;
                    int o00 = d0 * HW + h0 * W, o01 = d0 * HW + h1 * W;
                    int o10 = d1 * HW + h0 * W, o11 = d1 * HW + h1 * W;
                    float q0 = gimg[o00 + w0] * w00 + gimg[o00 + w1] * w01
                             + gimg[o01 + w0] * w10 + gimg[o01 + w1] * w11;
                    float q1 = gimg[o10 + w0] * w00 + gimg[o10 + w1] * w01
                             + gimg[o11 + w0] * w10 + gimg[o11 + w1] * w11;
                    acc[k] = gd * q0 + fd * q1;
                }
            }
        }
    };

    // ---- pass 0 ----
    asm volatile("s_waitcnt vmcnt(0)" ::: "memory");    // ch0 staged
    __builtin_amdgcn_s_barrier();
    float acc0[4];
    int fb0 = gather(acc0);
    fixup(imgb, acc0, fb0);
    *reinterpret_cast<float4*>(out + ((size_t)b * C + 0) * DHW + sidx) =
        make_float4(acc0[0], acc0[1], acc0[2], acc0[3]);

    // all waves done reading ch0 before overwrite
    __builtin_amdgcn_s_barrier();
    asm volatile("" ::: "memory");

    // ---- pass 1 ----
    issue_stage(imgb + DHW);
    asm volatile("s_waitcnt vmcnt(0)" ::: "memory");    // ch1 staged
    __builtin_amdgcn_s_barrier();
    float acc1[4];
    int fb1 = gather(acc1);
    fixup(imgb + DHW, acc1, fb1);
    *reinterpret_cast<float4*>(out + ((size_t)b * C + 1) * DHW + sidx) =
        make_float4(acc1[0], acc1[1], acc1[2], acc1[3]);
}

extern "C" void kernel_launch(void* const* d_in, const int* in_sizes, int n_in,
                              void* d_out, int out_size, void* d_ws, size_t ws_size,
                              hipStream_t stream) {
    const float* image = (const float*)d_in[0];
    const float* ddf   = (const float*)d_in[1];
    float* out = (float*)d_out;

    int grid = B * 512;   // 8x8x8 tiles of 16^3 per batch
    stn_kernel<<<grid, NT, 0, stream>>>(image, ddf, out);
}